// Round 1
// baseline (181.658 us; speedup 1.0000x reference)
//
#include <hip/hip_runtime.h>

// DiceLoss: fp32 inputs [B=16, C=3, H*W=262144], scalar fp32 output.
// num[c] = 2*sum_bn(x*t); den[c] = sum_bn(x^2) + sum_bn(t^2)
// out = 1 - mean_c((num[c]+eps)/(den[c]+eps))

#define HW 262144   // 512*512 = 2^18
#define NC 3
#define NB 16
#define EPSF 1e-5f

// ws layout: ws[2*c] = sum(x*t) for channel c, ws[2*c+1] = sum(x^2+t^2)

__global__ __launch_bounds__(256) void dice_partials(
    const float* __restrict__ x, const float* __restrict__ t,
    float* __restrict__ ws) {
  const int c = blockIdx.y;          // channel
  const int b = blockIdx.z;          // batch
  const size_t base = ((size_t)b * NC + c) * (size_t)HW;
  const float4* __restrict__ x4 = (const float4*)(x + base);
  const float4* __restrict__ t4 = (const float4*)(t + base);

  const int n4 = HW / 4;                       // 65536 float4 per (b,c) plane
  const int per_block = n4 / gridDim.x;        // e.g. 65536/64 = 1024
  const int start = blockIdx.x * per_block;

  float s_xt = 0.f, s_den = 0.f;
  for (int i = start + threadIdx.x; i < start + per_block; i += blockDim.x) {
    float4 a = x4[i];
    float4 g = t4[i];
    s_xt  += a.x * g.x + a.y * g.y + a.z * g.z + a.w * g.w;
    s_den += a.x * a.x + a.y * a.y + a.z * a.z + a.w * a.w
           + g.x * g.x + g.y * g.y + g.z * g.z + g.w * g.w;
  }

  // wave-64 shuffle reduction
  #pragma unroll
  for (int off = 32; off > 0; off >>= 1) {
    s_xt  += __shfl_down(s_xt, off);
    s_den += __shfl_down(s_den, off);
  }

  __shared__ float sm[8];            // 4 waves x 2 accumulators
  const int wave = threadIdx.x >> 6;
  const int lane = threadIdx.x & 63;
  if (lane == 0) { sm[wave * 2] = s_xt; sm[wave * 2 + 1] = s_den; }
  __syncthreads();

  if (threadIdx.x == 0) {
    float a0 = sm[0] + sm[2] + sm[4] + sm[6];
    float a1 = sm[1] + sm[3] + sm[5] + sm[7];
    atomicAdd(&ws[2 * c],     a0);   // device-scope by default on CDNA
    atomicAdd(&ws[2 * c + 1], a1);
  }
}

__global__ void dice_final(const float* __restrict__ ws, float* __restrict__ out) {
  float acc = 0.f;
  #pragma unroll
  for (int c = 0; c < NC; c++) {
    float num = 2.f * ws[2 * c] + EPSF;
    float den = ws[2 * c + 1] + EPSF;
    acc += num / den;
  }
  out[0] = 1.f - acc * (1.f / 3.f);
}

extern "C" void kernel_launch(void* const* d_in, const int* in_sizes, int n_in,
                              void* d_out, int out_size, void* d_ws, size_t ws_size,
                              hipStream_t stream) {
  const float* x = (const float*)d_in[0];   // input
  const float* t = (const float*)d_in[1];   // target
  float* out = (float*)d_out;
  float* ws  = (float*)d_ws;

  // ws is re-poisoned to 0xAA before every launch — zero the 6 accumulators.
  hipMemsetAsync(ws, 0, 6 * sizeof(float), stream);

  dim3 grid(64, NC, NB);   // 3072 blocks, each covers 1024 float4 of one (b,c) plane
  dice_partials<<<grid, 256, 0, stream>>>(x, t, ws);
  dice_final<<<1, 1, 0, stream>>>(ws, out);
}

// Round 2
// 115.048 us; speedup vs baseline: 1.5790x; 1.5790x over previous
//
#include <hip/hip_runtime.h>

// DiceLoss: fp32 inputs [B=16, C=3, HW=262144], scalar fp32 output.
// num[c] = 2*sum_bn(x*t); den[c] = sum_bn(x^2) + sum_bn(t^2)
// out = 1 - mean_c((num[c]+eps)/(den[c]+eps))
//
// Two-stage reduction, NO atomics (R1 showed 6144 same-line atomicAdds
// serialized to ~89us): stage 1 writes per-block float2 partials to ws,
// stage 2 (one block) reduces 1024 partials per channel + epilogue.

#define HW 262144          // 512*512
#define NC 3
#define NB 16
#define NBX 64             // blocks per (b,c) plane — compile-time so loop unrolls
#define PER_BLOCK (HW / 4 / NBX)   // 1024 float4 per block
#define NPART (NB * NBX)   // 1024 partials per channel
#define EPSF 1e-5f

// ws layout: float2 partial[c*NPART + b*NBX + bx] = {sum(x*t), sum(x^2+t^2)}

__global__ __launch_bounds__(256) void dice_partials(
    const float* __restrict__ x, const float* __restrict__ t,
    float2* __restrict__ part) {
  const int bx = blockIdx.x;
  const int c  = blockIdx.y;
  const int b  = blockIdx.z;
  const size_t base = ((size_t)b * NC + c) * (size_t)HW;
  const float4* __restrict__ x4 = (const float4*)(x + base);
  const float4* __restrict__ t4 = (const float4*)(t + base);

  const int start = bx * PER_BLOCK;

  float s_xt = 0.f, s_den = 0.f;
  #pragma unroll
  for (int k = 0; k < PER_BLOCK / 256; k++) {        // 4 iters, fully unrolled
    int i = start + threadIdx.x + k * 256;
    float4 a = x4[i];
    float4 g = t4[i];
    s_xt  += a.x * g.x + a.y * g.y + a.z * g.z + a.w * g.w;
    s_den += a.x * a.x + a.y * a.y + a.z * a.z + a.w * a.w
           + g.x * g.x + g.y * g.y + g.z * g.z + g.w * g.w;
  }

  // wave-64 shuffle reduction
  #pragma unroll
  for (int off = 32; off > 0; off >>= 1) {
    s_xt  += __shfl_down(s_xt, off);
    s_den += __shfl_down(s_den, off);
  }

  __shared__ float sm[8];
  const int wave = threadIdx.x >> 6;
  const int lane = threadIdx.x & 63;
  if (lane == 0) { sm[wave * 2] = s_xt; sm[wave * 2 + 1] = s_den; }
  __syncthreads();

  if (threadIdx.x == 0) {
    float2 p;
    p.x = sm[0] + sm[2] + sm[4] + sm[6];
    p.y = sm[1] + sm[3] + sm[5] + sm[7];
    part[c * NPART + b * NBX + bx] = p;   // plain store — overwrites 0xAA poison
  }
}

__global__ __launch_bounds__(256) void dice_final(
    const float2* __restrict__ part, float* __restrict__ out) {
  __shared__ float sm[8];
  float acc = 0.f;

  for (int c = 0; c < NC; c++) {
    float sx = 0.f, sd = 0.f;
    #pragma unroll
    for (int k = 0; k < NPART / 256; k++) {          // 4 iters
      float2 v = part[c * NPART + threadIdx.x + k * 256];
      sx += v.x;
      sd += v.y;
    }
    #pragma unroll
    for (int off = 32; off > 0; off >>= 1) {
      sx += __shfl_down(sx, off);
      sd += __shfl_down(sd, off);
    }
    const int wave = threadIdx.x >> 6;
    const int lane = threadIdx.x & 63;
    if (lane == 0) { sm[wave * 2] = sx; sm[wave * 2 + 1] = sd; }
    __syncthreads();
    if (threadIdx.x == 0) {
      float num = 2.f * (sm[0] + sm[2] + sm[4] + sm[6]) + EPSF;
      float den = (sm[1] + sm[3] + sm[5] + sm[7]) + EPSF;
      acc += num / den;
    }
    __syncthreads();   // sm reused next channel
  }

  if (threadIdx.x == 0) out[0] = 1.f - acc * (1.f / 3.f);
}

extern "C" void kernel_launch(void* const* d_in, const int* in_sizes, int n_in,
                              void* d_out, int out_size, void* d_ws, size_t ws_size,
                              hipStream_t stream) {
  const float* x = (const float*)d_in[0];
  const float* t = (const float*)d_in[1];
  float* out  = (float*)d_out;
  float2* part = (float2*)d_ws;   // 3072 float2 = 24 KB

  dim3 grid(NBX, NC, NB);         // 3072 blocks
  dice_partials<<<grid, 256, 0, stream>>>(x, t, part);
  dice_final<<<1, 256, 0, stream>>>(part, out);
}

// Round 3
// 114.677 us; speedup vs baseline: 1.5841x; 1.0032x over previous
//
#include <hip/hip_runtime.h>

// DiceLoss: fp32 inputs [B=16, C=3, HW=262144], scalar fp32 output.
// num[c] = 2*sum_bn(x*t); den[c] = sum_bn(x^2) + sum_bn(t^2)
// out = 1 - mean_c((num[c]+eps)/(den[c]+eps))
//
// Two-stage reduction, no atomics (R1: 6144 same-line atomicAdds serialized
// to 89us). R3: NBX 64->32 — 16 independent float4 loads in flight per
// thread (R1/R2 stage 1 was memory-latency-bound: VALUBusy 3%, occ 52%,
// only 8 loads of ILP). Measured dur_us includes ~73us of harness reset
// (256MiB ws poison fill @41us + ~100MB input restore) we cannot control.

#define HW 262144          // 512*512
#define NC 3
#define NB 16
#define NBX 32             // blocks per (b,c) plane — compile-time so loop unrolls
#define ITERS (HW / 4 / NBX / 256)   // 8 unrolled float4-pair loads per thread
#define NPART (NB * NBX)   // 512 partials per channel
#define EPSF 1e-5f

// ws layout: float2 partial[c*NPART + b*NBX + bx] = {sum(x*t), sum(x^2+t^2)}

__global__ __launch_bounds__(256) void dice_partials(
    const float* __restrict__ x, const float* __restrict__ t,
    float2* __restrict__ part) {
  const int bx = blockIdx.x;
  const int c  = blockIdx.y;
  const int b  = blockIdx.z;
  const size_t base = ((size_t)b * NC + c) * (size_t)HW;
  const float4* __restrict__ x4 = (const float4*)(x + base);
  const float4* __restrict__ t4 = (const float4*)(t + base);

  const int start = bx * (ITERS * 256) + threadIdx.x;

  // Issue all 16 loads before reducing — max memory-level parallelism.
  float4 a[ITERS], g[ITERS];
  #pragma unroll
  for (int k = 0; k < ITERS; k++) a[k] = x4[start + k * 256];
  #pragma unroll
  for (int k = 0; k < ITERS; k++) g[k] = t4[start + k * 256];

  float s_xt = 0.f, s_den = 0.f;
  #pragma unroll
  for (int k = 0; k < ITERS; k++) {
    s_xt  += a[k].x * g[k].x + a[k].y * g[k].y + a[k].z * g[k].z + a[k].w * g[k].w;
    s_den += a[k].x * a[k].x + a[k].y * a[k].y + a[k].z * a[k].z + a[k].w * a[k].w
           + g[k].x * g[k].x + g[k].y * g[k].y + g[k].z * g[k].z + g[k].w * g[k].w;
  }

  // wave-64 shuffle reduction
  #pragma unroll
  for (int off = 32; off > 0; off >>= 1) {
    s_xt  += __shfl_down(s_xt, off);
    s_den += __shfl_down(s_den, off);
  }

  __shared__ float sm[8];
  const int wave = threadIdx.x >> 6;
  const int lane = threadIdx.x & 63;
  if (lane == 0) { sm[wave * 2] = s_xt; sm[wave * 2 + 1] = s_den; }
  __syncthreads();

  if (threadIdx.x == 0) {
    float2 p;
    p.x = sm[0] + sm[2] + sm[4] + sm[6];
    p.y = sm[1] + sm[3] + sm[5] + sm[7];
    part[c * NPART + b * NBX + bx] = p;   // plain store — overwrites 0xAA poison
  }
}

__global__ __launch_bounds__(256) void dice_final(
    const float2* __restrict__ part, float* __restrict__ out) {
  __shared__ float sm[8];
  float acc = 0.f;

  for (int c = 0; c < NC; c++) {
    float sx = 0.f, sd = 0.f;
    #pragma unroll
    for (int k = 0; k < NPART / 256; k++) {          // 2 iters
      float2 v = part[c * NPART + threadIdx.x + k * 256];
      sx += v.x;
      sd += v.y;
    }
    #pragma unroll
    for (int off = 32; off > 0; off >>= 1) {
      sx += __shfl_down(sx, off);
      sd += __shfl_down(sd, off);
    }
    const int wave = threadIdx.x >> 6;
    const int lane = threadIdx.x & 63;
    if (lane == 0) { sm[wave * 2] = sx; sm[wave * 2 + 1] = sd; }
    __syncthreads();
    if (threadIdx.x == 0) {
      float num = 2.f * (sm[0] + sm[2] + sm[4] + sm[6]) + EPSF;
      float den = (sm[1] + sm[3] + sm[5] + sm[7]) + EPSF;
      acc += num / den;
    }
    __syncthreads();   // sm reused next channel
  }

  if (threadIdx.x == 0) out[0] = 1.f - acc * (1.f / 3.f);
}

extern "C" void kernel_launch(void* const* d_in, const int* in_sizes, int n_in,
                              void* d_out, int out_size, void* d_ws, size_t ws_size,
                              hipStream_t stream) {
  const float* x = (const float*)d_in[0];
  const float* t = (const float*)d_in[1];
  float* out  = (float*)d_out;
  float2* part = (float2*)d_ws;   // 1536 float2 = 12 KB

  dim3 grid(NBX, NC, NB);         // 1536 blocks
  dice_partials<<<grid, 256, 0, stream>>>(x, t, part);
  dice_final<<<1, 256, 0, stream>>>(part, out);
}